// Round 2
// baseline (447.004 us; speedup 1.0000x reference)
//
#include <hip/hip_runtime.h>
#include <hip/hip_bf16.h>

#define B_N 128
#define T_N 2048
#define H_N 512

typedef __attribute__((ext_vector_type(8))) short bf16x8;   // 8 bf16 = 4 VGPRs
typedef __attribute__((ext_vector_type(4))) float f32x4;    // MFMA acc

// RNE f32 -> bf16 (low 16 bits of return)
__device__ __forceinline__ unsigned int f2bf(float f) {
    unsigned int u = __float_as_uint(f);
    u += 0x7fffu + ((u >> 16) & 1u);
    return u >> 16;
}

__device__ __forceinline__ float tanh_fast(float x) {
    // inputs here are always >= 0 (sum of two relus), clamp for safety
    x = fminf(fmaxf(x, -15.f), 15.f);
    float e = __expf(2.f * x);
    float r = __builtin_amdgcn_rcpf(e + 1.f);
    return 1.f - 2.f * r;
}

// ---------------------------------------------------------------------------
// K2: convert w2 (512x512 f32, row g major) -> bf16, pre-swizzled within each
// 1024B row:  dst_byte(g,k) = g*1024 + ((k*2) ^ ((g&7)<<4))
// k_scores stages these rows LINEARLY into LDS (global_load_lds); the MFMA
// fragment read applies byte^((row&7)<<4), cancelling the pre-swizzle.
// Swizzle count along the data path must be EVEN (prep + read). [R1 bugfix]
// ---------------------------------------------------------------------------
__global__ void k_w2prep(const float* __restrict__ w2, unsigned short* __restrict__ w2sw) {
    int c = blockIdx.x * 256 + threadIdx.x;      // 32768 chunks of 8 elems
    int g = c >> 6, kc = c & 63;
    const float4* s = reinterpret_cast<const float4*>(w2 + (size_t)g * H_N + kc * 8);
    float4 f0 = s[0], f1 = s[1];
    uint4 p;
    p.x = f2bf(f0.x) | (f2bf(f0.y) << 16);
    p.y = f2bf(f0.z) | (f2bf(f0.w) << 16);
    p.z = f2bf(f1.x) | (f2bf(f1.y) << 16);
    p.w = f2bf(f1.z) | (f2bf(f1.w) << 16);
    *reinterpret_cast<uint4*>(reinterpret_cast<char*>(w2sw) + (size_t)g * 1024 +
                              (((kc * 16) ^ ((g & 7) << 4)))) = p;
}

// ---------------------------------------------------------------------------
// K1: q_h[b][g] = relu(sum_h query[b][h] * w1[g][h])   (f32, tiny)
// ---------------------------------------------------------------------------
__global__ void k_qh(const float* __restrict__ query, const float* __restrict__ w1,
                     float* __restrict__ qh) {
    int b = blockIdx.x;
    int g = threadIdx.x;                          // 512 threads
    __shared__ float q[H_N];
    q[g] = query[(size_t)b * H_N + g];
    __syncthreads();
    const float4* w = reinterpret_cast<const float4*>(w1 + (size_t)g * H_N);
    float acc = 0.f;
#pragma unroll 4
    for (int i = 0; i < H_N / 4; ++i) {
        float4 wv = w[i];
        acc += q[4*i] * wv.x + q[4*i+1] * wv.y + q[4*i+2] * wv.z + q[4*i+3] * wv.w;
    }
    qh[(size_t)b * H_N + g] = fmaxf(acc, 0.f);
}

// ---------------------------------------------------------------------------
// K3: scores[b][t] = sum_g w_out[g] * tanh(q_h[b][g] + relu(key[b][t]·w2[g]))
// BM=128 t-rows/block, N swept in 2 chunks of 256, K=512 in 8 steps of 64.
// 512 threads = 8 waves, wave tile 64t x 64g (4x4 MFMA 16x16x32 frags).
// A (key) reg-staged f32->bf16 into XOR-swizzled LDS; B via global_load_lds
// (LINEAR copy) from the pre-swizzled w2sw. Per-g reduction kept in
// registers, finished with shfl_xor + LDS cross-wave combine.
// ---------------------------------------------------------------------------
__global__ __launch_bounds__(512) void k_scores(
    const float* __restrict__ key, const unsigned short* __restrict__ w2sw,
    const float* __restrict__ qh, const float* __restrict__ w_out,
    float* __restrict__ scores)
{
    const int b    = blockIdx.y;
    const int t0   = blockIdx.x * 128;
    const int tid  = threadIdx.x;
    const int wid  = tid >> 6;
    const int lane = tid & 63;
    const int lrow = lane & 15;       // fragment row/col index
    const int lq   = lane >> 4;       // 0..3 k-group / acc row group
    const int wr   = wid >> 2;        // 0..1  (t half)
    const int wc   = wid & 3;         // 0..3  (g quarter within 256-chunk)
    const int swz  = (lrow & 7) << 4; // LDS XOR swizzle for frag reads

    __shared__ __align__(16) unsigned short Ab[128 * 64]; // 16 KB, key tile bf16
    __shared__ __align__(16) unsigned short Bb[256 * 64]; // 32 KB, w2 tile bf16
    __shared__ float qhs[H_N];
    __shared__ float wouts[H_N];
    __shared__ float sscore[4][128];

    qhs[tid]   = qh[(size_t)b * H_N + tid];
    wouts[tid] = w_out[tid];

    float pscore[4][4] = {};                      // [m][r] partial over all g
    const float* keyb = key + ((size_t)b * T_N + t0) * H_N;
    const char*  w2sb = reinterpret_cast<const char*>(w2sw);
    const f32x4  vzero = {0.f, 0.f, 0.f, 0.f};

    for (int ns = 0; ns < 2; ++ns) {
        const int g0 = ns * 256;
        f32x4 acc[4][4];
#pragma unroll
        for (int m = 0; m < 4; ++m)
#pragma unroll
            for (int n = 0; n < 4; ++n) acc[m][n] = vzero;

        for (int ks = 0; ks < 8; ++ks) {
            const int kk = ks * 64;
            // ---- stage A: 128x64 f32 -> bf16 -> swizzled LDS ----
#pragma unroll
            for (int i = 0; i < 2; ++i) {
                int cc   = i * 512 + tid;          // 0..1023 16B chunks
                int row  = cc >> 3;
                int slot = cc & 7;
                const float* src = keyb + (size_t)row * H_N + kk + slot * 8;
                float4 f0 = *reinterpret_cast<const float4*>(src);
                float4 f1 = *reinterpret_cast<const float4*>(src + 4);
                uint4 p;
                p.x = f2bf(f0.x) | (f2bf(f0.y) << 16);
                p.y = f2bf(f0.z) | (f2bf(f0.w) << 16);
                p.z = f2bf(f1.x) | (f2bf(f1.y) << 16);
                p.w = f2bf(f1.z) | (f2bf(f1.w) << 16);
                *reinterpret_cast<uint4*>(reinterpret_cast<char*>(Ab) + row * 128 +
                                          ((slot * 16) ^ ((row & 7) << 4))) = p;
            }
            // ---- stage B: 256x64 bf16 via global_load_lds ----
            // LINEAR copy of pre-swizzled rows (prep-swz + read-swz cancel).
#pragma unroll
            for (int i = 0; i < 4; ++i) {
                int c0   = (wid * 4 + i) * 64;     // wave-uniform chunk base
                int c    = c0 + lane;
                int row  = c >> 3;
                int slot = c & 7;
                const char* src = w2sb + (size_t)(g0 + row) * 1024 + kk * 2 + slot * 16;
                __builtin_amdgcn_global_load_lds(
                    (const __attribute__((address_space(1))) void*)src,
                    (__attribute__((address_space(3))) void*)(reinterpret_cast<char*>(Bb) + c0 * 16),
                    16, 0, 0);
            }
            __syncthreads();
            // ---- MFMA: 2 k-subtiles x 4m x 4n ----
#pragma unroll
            for (int ksub = 0; ksub < 2; ++ksub) {
                const int kb = ksub * 64 + lq * 16;
                bf16x8 a[4], bv[4];
#pragma unroll
                for (int m = 0; m < 4; ++m) {
                    int row = wr * 64 + m * 16 + lrow;
                    a[m] = *reinterpret_cast<const bf16x8*>(
                        reinterpret_cast<const char*>(Ab) + row * 128 + (kb ^ swz));
                }
#pragma unroll
                for (int n = 0; n < 4; ++n) {
                    int row = wc * 64 + n * 16 + lrow;
                    bv[n] = *reinterpret_cast<const bf16x8*>(
                        reinterpret_cast<const char*>(Bb) + row * 128 + (kb ^ swz));
                }
#pragma unroll
                for (int m = 0; m < 4; ++m)
#pragma unroll
                    for (int n = 0; n < 4; ++n)
                        acc[m][n] = __builtin_amdgcn_mfma_f32_16x16x32_bf16(
                            a[m], bv[n], acc[m][n], 0, 0, 0);
            }
            __syncthreads();
        }
        // ---- epilogue for this 256-g chunk: w_out * tanh(qh + relu(acc)) ----
#pragma unroll
        for (int n = 0; n < 4; ++n) {
            int g = g0 + wc * 64 + n * 16 + lrow;
            float wo = wouts[g];
            float qv = qhs[g];
#pragma unroll
            for (int m = 0; m < 4; ++m)
#pragma unroll
                for (int r = 0; r < 4; ++r) {
                    float x = qv + fmaxf(acc[m][n][r], 0.f);
                    pscore[m][r] = fmaf(wo, tanh_fast(x), pscore[m][r]);
                }
        }
    }
    // ---- reduce over the 16 fragment columns (lanes) then across g-waves ----
#pragma unroll
    for (int m = 0; m < 4; ++m)
#pragma unroll
        for (int r = 0; r < 4; ++r) {
            float v = pscore[m][r];
            v += __shfl_xor(v, 1);
            v += __shfl_xor(v, 2);
            v += __shfl_xor(v, 4);
            v += __shfl_xor(v, 8);
            if (lrow == 0) sscore[wc][wr * 64 + m * 16 + lq * 4 + r] = v;
        }
    __syncthreads();
    if (tid < 128)
        scores[(size_t)b * T_N + t0 + tid] =
            sscore[0][tid] + sscore[1][tid] + sscore[2][tid] + sscore[3][tid];
}

// ---------------------------------------------------------------------------
// K4: softmax over T per batch row (f32)
// ---------------------------------------------------------------------------
__global__ void k_softmax(const float* __restrict__ scores, float* __restrict__ attn) {
    int b = blockIdx.x, tid = threadIdx.x;      // 256 threads, 8 elems each
    __shared__ float red[256];
    float v[8];
    float mx = -3.4e38f;
#pragma unroll
    for (int i = 0; i < 8; ++i) {
        v[i] = scores[(size_t)b * T_N + i * 256 + tid];
        mx = fmaxf(mx, v[i]);
    }
    red[tid] = mx; __syncthreads();
    for (int s = 128; s > 0; s >>= 1) {
        if (tid < s) red[tid] = fmaxf(red[tid], red[tid + s]);
        __syncthreads();
    }
    mx = red[0];
    __syncthreads();
    float sum = 0.f;
#pragma unroll
    for (int i = 0; i < 8; ++i) { v[i] = __expf(v[i] - mx); sum += v[i]; }
    red[tid] = sum; __syncthreads();
    for (int s = 128; s > 0; s >>= 1) {
        if (tid < s) red[tid] += red[tid + s];
        __syncthreads();
    }
    float inv = 1.f / red[0];
#pragma unroll
    for (int i = 0; i < 8; ++i)
        attn[(size_t)b * T_N + i * 256 + tid] = v[i] * inv;
}

// ---------------------------------------------------------------------------
// K5: partial[b][c][h] = sum_{t in chunk c} attn[b][t] * key[b][t][h]
// 16 T-chunks of 128 per batch; coalesced float2 streams. Memory-bound.
// ---------------------------------------------------------------------------
__global__ void k_wsum(const float* __restrict__ key, const float* __restrict__ attn,
                       float* __restrict__ partial) {
    int c = blockIdx.x, b = blockIdx.y, tid = threadIdx.x; // 256 threads
    __shared__ float at[128];
    if (tid < 128) at[tid] = attn[(size_t)b * T_N + c * 128 + tid];
    __syncthreads();
    const float2* kp = reinterpret_cast<const float2*>(
        key + ((size_t)b * T_N + (size_t)c * 128) * H_N) + tid;
    float ax = 0.f, ay = 0.f;
#pragma unroll 4
    for (int t = 0; t < 128; ++t) {
        float2 kv = kp[(size_t)t * 256];
        float a = at[t];
        ax = fmaf(a, kv.x, ax);
        ay = fmaf(a, kv.y, ay);
    }
    float2 o; o.x = ax; o.y = ay;
    *reinterpret_cast<float2*>(partial + ((size_t)(b * 16 + c)) * H_N + tid * 2) = o;
}

// ---------------------------------------------------------------------------
// K6: out[b][h] = sum_c partial[b][c][h]
// ---------------------------------------------------------------------------
__global__ void k_reduce(const float* __restrict__ partial, float* __restrict__ out) {
    int idx = blockIdx.x * 256 + threadIdx.x;   // 65536 outputs
    int b = idx >> 9, h = idx & 511;
    float s = 0.f;
#pragma unroll
    for (int c = 0; c < 16; ++c) s += partial[((size_t)(b * 16 + c)) * H_N + h];
    out[idx] = s;
}

extern "C" void kernel_launch(void* const* d_in, const int* in_sizes, int n_in,
                              void* d_out, int out_size, void* d_ws, size_t ws_size,
                              hipStream_t stream) {
    const float* query = (const float*)d_in[0];
    const float* key   = (const float*)d_in[1];
    const float* w1    = (const float*)d_in[2];
    const float* w2    = (const float*)d_in[3];
    const float* w_out = (const float*)d_in[4];
    float* out = (float*)d_out;

    char* ws = (char*)d_ws;
    unsigned short* w2sw = (unsigned short*)(ws);            // 512 KB
    float* qh      = (float*)(ws + 524288);                  // 256 KB
    float* scores  = (float*)(ws + 786432);                  // 1 MB
    float* attn    = (float*)(ws + 1835008);                 // 1 MB
    float* partial = (float*)(ws + 2883584);                 // 4 MB

    hipLaunchKernelGGL(k_w2prep,  dim3(128),      dim3(256), 0, stream, w2, w2sw);
    hipLaunchKernelGGL(k_qh,      dim3(128),      dim3(512), 0, stream, query, w1, qh);
    hipLaunchKernelGGL(k_scores,  dim3(16, 128),  dim3(512), 0, stream, key, w2sw, qh, w_out, scores);
    hipLaunchKernelGGL(k_softmax, dim3(128),      dim3(256), 0, stream, scores, attn);
    hipLaunchKernelGGL(k_wsum,    dim3(16, 128),  dim3(256), 0, stream, key, attn, partial);
    hipLaunchKernelGGL(k_reduce,  dim3(256),      dim3(256), 0, stream, partial, out);
}

// Round 3
// 373.188 us; speedup vs baseline: 1.1978x; 1.1978x over previous
//
#include <hip/hip_runtime.h>
#include <hip/hip_bf16.h>

#define B_N 128
#define T_N 2048
#define H_N 512

typedef __attribute__((ext_vector_type(8))) short bf16x8;   // 8 bf16 = 4 VGPRs
typedef __attribute__((ext_vector_type(4))) float f32x4;    // MFMA acc

union U4 { unsigned int i[4]; bf16x8 v; };

// RNE f32 -> bf16 (low 16 bits) — host-side-quality scalar path for prep kernels
__device__ __forceinline__ unsigned int f2bf(float f) {
    unsigned int u = __float_as_uint(f);
    u += 0x7fffu + ((u >> 16) & 1u);
    return u >> 16;
}

// packed f32x2 -> bf16x2 (RNE), single VALU inst
__device__ __forceinline__ unsigned int cvtpk(float lo, float hi) {
    unsigned int r;
    asm("v_cvt_pk_bf16_f32 %0, %1, %2" : "=v"(r) : "v"(lo), "v"(hi));
    return r;
}

// x >= 0 always here (relu+relu); exp overflow degrades gracefully to 1.0
__device__ __forceinline__ float tanh_fast(float x) {
    float e = __expf(2.f * x);
    float r = __builtin_amdgcn_rcpf(e + 1.f);
    return 1.f - 2.f * r;
}

// ---------------------------------------------------------------------------
// K2: w2 (512x512 f32) -> bf16, pre-swizzled within each 1024B row:
// dst_byte(g,k) = g*1024 + ((k*2) ^ ((g&7)<<4)). Staged LINEARLY into LDS;
// fragment read applies byte^((g&7)<<4), cancelling. (Even swizzle count.)
// ---------------------------------------------------------------------------
__global__ void k_w2prep(const float* __restrict__ w2, unsigned short* __restrict__ w2sw) {
    int c = blockIdx.x * 256 + threadIdx.x;      // 32768 chunks of 8 elems
    int g = c >> 6, kc = c & 63;
    const float4* s = reinterpret_cast<const float4*>(w2 + (size_t)g * H_N + kc * 8);
    float4 f0 = s[0], f1 = s[1];
    uint4 p;
    p.x = f2bf(f0.x) | (f2bf(f0.y) << 16);
    p.y = f2bf(f0.z) | (f2bf(f0.w) << 16);
    p.z = f2bf(f1.x) | (f2bf(f1.y) << 16);
    p.w = f2bf(f1.z) | (f2bf(f1.w) << 16);
    *reinterpret_cast<uint4*>(reinterpret_cast<char*>(w2sw) + (size_t)g * 1024 +
                              (((kc * 16) ^ ((g & 7) << 4)))) = p;
}

// ---------------------------------------------------------------------------
// K1: q_h[b][g] = relu(query[b]·w1[g])   (f32, tiny)
// ---------------------------------------------------------------------------
__global__ void k_qh(const float* __restrict__ query, const float* __restrict__ w1,
                     float* __restrict__ qh) {
    int b = blockIdx.x;
    int g = threadIdx.x;                          // 512 threads
    __shared__ float q[H_N];
    q[g] = query[(size_t)b * H_N + g];
    __syncthreads();
    const float4* w = reinterpret_cast<const float4*>(w1 + (size_t)g * H_N);
    float acc = 0.f;
#pragma unroll 4
    for (int i = 0; i < H_N / 4; ++i) {
        float4 wv = w[i];
        acc += q[4*i] * wv.x + q[4*i+1] * wv.y + q[4*i+2] * wv.z + q[4*i+3] * wv.w;
    }
    qh[(size_t)b * H_N + g] = fmaxf(acc, 0.f);
}

// ---------------------------------------------------------------------------
// K3: scores[b][t] = sum_g w_out[g]*tanh(qh[b][g] + relu(key[b][t]·w2[g]))
// 128 t-rows/block, 2 N-sweeps of 256 g, 8 K-steps of 64 per sweep.
// BOTH operands staged by global_load_lds (fire-and-forget DMA):
//   A: key tile 128x64 raw f32 (32 KB), source-side XOR swizzle
//      (16B slot ^ (t-row & 7)); f32->bf16 via v_cvt_pk at fragment read.
//   B: pre-swizzled w2sw, linear copy (32 KB).
// LDS exactly 64 KB -> 2 blocks/CU; no VALU in stage phase at all.
// stage(s+1) issued right after the post-MFMA barrier; the per-sweep tanh
// epilogue (s=7,15) overlaps the deepest part of the DMA latency.
// ---------------------------------------------------------------------------
__global__ __launch_bounds__(512, 4) void k_scores(
    const float* __restrict__ key, const unsigned short* __restrict__ w2sw,
    const float* __restrict__ qh, const float* __restrict__ w_out,
    float* __restrict__ scores)
{
    const int b    = blockIdx.y;
    const int t0   = blockIdx.x * 128;
    const int tid  = threadIdx.x;
    const int wid  = tid >> 6;
    const int lane = tid & 63;
    const int lrow = lane & 15;        // fragment row/col
    const int lq   = lane >> 4;        // 0..3 k-group
    const int wr   = wid >> 2;         // 0..1 t half
    const int wc   = wid & 3;          // 0..3 g quarter
    const int swz8 = lrow & 7;         // == (tile_row & 7) for all frag rows
    const int swzB = swz8 << 4;        // byte XOR for B reads

    __shared__ __align__(16) char smem[65536];   // [0,32K): A f32 tile; [32K,64K): B bf16
    char* Af = smem;
    char* Bf = smem + 32768;
    float* sscore = reinterpret_cast<float*>(smem);  // aliases Af, used post-loop

    const char* keybB = reinterpret_cast<const char*>(key + ((size_t)b * T_N + t0) * H_N);
    const char* w2sb  = reinterpret_cast<const char*>(w2sw);

    // fire-and-forget staging of step s (ns = s>>3, kk = (s&7)*64 elems)
    auto stage = [&](int s) {
        const int ns = s >> 3;
        const int kk = (s & 7) << 6;
        // A: 128 rows x 64 f32 = 2048 16B slots (16 per row)
#pragma unroll
        for (int i = 0; i < 4; ++i) {
            int c0   = i * 512 + wid * 64;           // wave-uniform
            int c    = c0 + lane;
            int row  = c >> 4;
            int slot = c & 15;
            const char* src = keybB + (size_t)row * 2048 + (size_t)kk * 4 +
                              ((slot ^ (row & 7)) << 4);
            __builtin_amdgcn_global_load_lds(
                (const __attribute__((address_space(1))) void*)src,
                (__attribute__((address_space(3))) void*)(Af + c0 * 16), 16, 0, 0);
        }
        // B: 256 rows x 64 bf16 = 2048 16B slots (8 per row), linear copy
#pragma unroll
        for (int i = 0; i < 4; ++i) {
            int c0   = (wid * 4 + i) * 64;           // wave-uniform
            int c    = c0 + lane;
            int row  = c >> 3;
            int slot = c & 7;
            const char* src = w2sb + (size_t)((ns << 8) + row) * 1024 + kk * 2 + slot * 16;
            __builtin_amdgcn_global_load_lds(
                (const __attribute__((address_space(1))) void*)src,
                (__attribute__((address_space(3))) void*)(Bf + c0 * 16), 16, 0, 0);
        }
    };

    float pscore[4][4] = {};        // [m][r] partials over all g
    f32x4 acc[4][4];
#pragma unroll
    for (int m = 0; m < 4; ++m)
#pragma unroll
        for (int n = 0; n < 4; ++n) acc[m][n] = f32x4{0.f, 0.f, 0.f, 0.f};

    stage(0);

    for (int s = 0; s < 16; ++s) {
        __syncthreads();            // drains DMA (vmcnt) + writes: LDS(s) ready

        // ---- compute step s: 2 k-subtiles x (4m x 4n) MFMA ----
#pragma unroll
        for (int ksub = 0; ksub < 2; ++ksub) {
            bf16x8 bv[4];
#pragma unroll
            for (int n = 0; n < 4; ++n) {
                int row = wc * 64 + n * 16 + lrow;
                bv[n] = *reinterpret_cast<const bf16x8*>(
                    Bf + row * 128 + ((ksub * 64 + lq * 16) ^ swzB));
            }
#pragma unroll
            for (int m = 0; m < 4; ++m) {
                int row = wr * 64 + m * 16 + lrow;
                int sl  = ksub * 8 + lq * 2;
                const char* base = Af + row * 256;
                float4 f0 = *reinterpret_cast<const float4*>(base + ((sl ^ swz8) << 4));
                float4 f1 = *reinterpret_cast<const float4*>(base + (((sl + 1) ^ swz8) << 4));
                U4 u;
                u.i[0] = cvtpk(f0.x, f0.y);
                u.i[1] = cvtpk(f0.z, f0.w);
                u.i[2] = cvtpk(f1.x, f1.y);
                u.i[3] = cvtpk(f1.z, f1.w);
#pragma unroll
                for (int n = 0; n < 4; ++n)
                    acc[m][n] = __builtin_amdgcn_mfma_f32_16x16x32_bf16(
                        u.v, bv[n], acc[m][n], 0, 0, 0);
            }
        }
        __syncthreads();            // all LDS reads of step s done

        if (s < 15) stage(s + 1);   // DMA in flight through epilogue / next drain

        if ((s & 7) == 7) {
            // ---- per-sweep epilogue: pscore += w_out * tanh(qh + relu(acc)) ----
            const int g0 = (s >> 3) << 8;
#pragma unroll
            for (int n = 0; n < 4; ++n) {
                int g = g0 + wc * 64 + n * 16 + lrow;
                float wo = w_out[g];
                float qv = qh[(size_t)b * H_N + g];
#pragma unroll
                for (int m = 0; m < 4; ++m) {
#pragma unroll
                    for (int r = 0; r < 4; ++r) {
                        float x = qv + fmaxf(acc[m][n][r], 0.f);
                        pscore[m][r] = fmaf(wo, tanh_fast(x), pscore[m][r]);
                    }
                    acc[m][n] = f32x4{0.f, 0.f, 0.f, 0.f};   // reset for next sweep
                }
            }
        }
    }

    // ---- reduce over 16 fragment columns (lanes), then across g-waves ----
#pragma unroll
    for (int m = 0; m < 4; ++m)
#pragma unroll
        for (int r = 0; r < 4; ++r) {
            float v = pscore[m][r];
            v += __shfl_xor(v, 1);
            v += __shfl_xor(v, 2);
            v += __shfl_xor(v, 4);
            v += __shfl_xor(v, 8);
            if (lrow == 0)
                sscore[wc * 128 + wr * 64 + m * 16 + lq * 4 + r] = v;
        }
    __syncthreads();
    if (tid < 128)
        scores[(size_t)b * T_N + t0 + tid] =
            sscore[0 * 128 + tid] + sscore[1 * 128 + tid] +
            sscore[2 * 128 + tid] + sscore[3 * 128 + tid];
}

// ---------------------------------------------------------------------------
// K4: softmax over T per batch row (f32)
// ---------------------------------------------------------------------------
__global__ void k_softmax(const float* __restrict__ scores, float* __restrict__ attn) {
    int b = blockIdx.x, tid = threadIdx.x;      // 256 threads, 8 elems each
    __shared__ float red[256];
    float v[8];
    float mx = -3.4e38f;
#pragma unroll
    for (int i = 0; i < 8; ++i) {
        v[i] = scores[(size_t)b * T_N + i * 256 + tid];
        mx = fmaxf(mx, v[i]);
    }
    red[tid] = mx; __syncthreads();
    for (int s = 128; s > 0; s >>= 1) {
        if (tid < s) red[tid] = fmaxf(red[tid], red[tid + s]);
        __syncthreads();
    }
    mx = red[0];
    __syncthreads();
    float sum = 0.f;
#pragma unroll
    for (int i = 0; i < 8; ++i) { v[i] = __expf(v[i] - mx); sum += v[i]; }
    red[tid] = sum; __syncthreads();
    for (int s = 128; s > 0; s >>= 1) {
        if (tid < s) red[tid] += red[tid + s];
        __syncthreads();
    }
    float inv = 1.f / red[0];
#pragma unroll
    for (int i = 0; i < 8; ++i)
        attn[(size_t)b * T_N + i * 256 + tid] = v[i] * inv;
}

// ---------------------------------------------------------------------------
// K5: partial[b][c][h] = sum_{t in chunk c} attn[b][t] * key[b][t][h]
// ---------------------------------------------------------------------------
__global__ void k_wsum(const float* __restrict__ key, const float* __restrict__ attn,
                       float* __restrict__ partial) {
    int c = blockIdx.x, b = blockIdx.y, tid = threadIdx.x; // 256 threads
    __shared__ float at[128];
    if (tid < 128) at[tid] = attn[(size_t)b * T_N + c * 128 + tid];
    __syncthreads();
    const float2* kp = reinterpret_cast<const float2*>(
        key + ((size_t)b * T_N + (size_t)c * 128) * H_N) + tid;
    float ax = 0.f, ay = 0.f;
#pragma unroll 4
    for (int t = 0; t < 128; ++t) {
        float2 kv = kp[(size_t)t * 256];
        float a = at[t];
        ax = fmaf(a, kv.x, ax);
        ay = fmaf(a, kv.y, ay);
    }
    float2 o; o.x = ax; o.y = ay;
    *reinterpret_cast<float2*>(partial + ((size_t)(b * 16 + c)) * H_N + tid * 2) = o;
}

// ---------------------------------------------------------------------------
// K6: out[b][h] = sum_c partial[b][c][h]
// ---------------------------------------------------------------------------
__global__ void k_reduce(const float* __restrict__ partial, float* __restrict__ out) {
    int idx = blockIdx.x * 256 + threadIdx.x;   // 65536 outputs
    int b = idx >> 9, h = idx & 511;
    float s = 0.f;
#pragma unroll
    for (int c = 0; c < 16; ++c) s += partial[((size_t)(b * 16 + c)) * H_N + h];
    out[idx] = s;
}

extern "C" void kernel_launch(void* const* d_in, const int* in_sizes, int n_in,
                              void* d_out, int out_size, void* d_ws, size_t ws_size,
                              hipStream_t stream) {
    const float* query = (const float*)d_in[0];
    const float* key   = (const float*)d_in[1];
    const float* w1    = (const float*)d_in[2];
    const float* w2    = (const float*)d_in[3];
    const float* w_out = (const float*)d_in[4];
    float* out = (float*)d_out;

    char* ws = (char*)d_ws;
    unsigned short* w2sw = (unsigned short*)(ws);            // 512 KB
    float* qh      = (float*)(ws + 524288);                  // 256 KB
    float* scores  = (float*)(ws + 786432);                  // 1 MB
    float* attn    = (float*)(ws + 1835008);                 // 1 MB
    float* partial = (float*)(ws + 2883584);                 // 4 MB

    hipLaunchKernelGGL(k_w2prep,  dim3(128),      dim3(256), 0, stream, w2, w2sw);
    hipLaunchKernelGGL(k_qh,      dim3(128),      dim3(512), 0, stream, query, w1, qh);
    hipLaunchKernelGGL(k_scores,  dim3(16, 128),  dim3(512), 0, stream, key, w2sw, qh, w_out, scores);
    hipLaunchKernelGGL(k_softmax, dim3(128),      dim3(256), 0, stream, scores, attn);
    hipLaunchKernelGGL(k_wsum,    dim3(16, 128),  dim3(256), 0, stream, key, attn, partial);
    hipLaunchKernelGGL(k_reduce,  dim3(256),      dim3(256), 0, stream, partial, out);
}